// Round 3
// 335.984 us; speedup vs baseline: 1.0818x; 1.0818x over previous
//
#include <hip/hip_runtime.h>
#include <hip/hip_bf16.h>

#define DM 1024
#define SEQ 2048
#define NB 4
#define NH 16
#define DKV 64

typedef unsigned short u16;
typedef unsigned int u32;
typedef __attribute__((ext_vector_type(8))) short bf16x8;
typedef __attribute__((ext_vector_type(4))) float f32x4;

__device__ __forceinline__ u16 f2bf(float f) {
    union { float f; unsigned u; } x; x.f = f;
    unsigned r = x.u + 0x7fffu + ((x.u >> 16) & 1u);   // RNE
    return (u16)(r >> 16);
}
// fast round-half-up bf16 (error <= 0.5 ulp)
__device__ __forceinline__ u16 f2bf1(float f) {
    union { float f; unsigned u; } x; x.f = f;
    return (u16)((x.u + 0x8000u) >> 16);
}
// pack two floats -> (bf16(b)<<16)|bf16(a): 1 v_perm + 2 adds (round-half-up, ~unbiased)
// NOTE: v_cvt_pk_bf16_f32 inline-asm was tried (rounds 1-2) and FAILED numerically
// (absmax 6.3e-3 vs 2.3e-3 threshold) even when confined to the softmax-P path where
// truncation bias should cancel. Its conversion semantics on gfx950 are unverified
// in this harness -> banned here. pack2bf is the proven path.
__device__ __forceinline__ u32 pack2bf(float a, float b) {
    union { float f; unsigned u; } xa, xb; xa.f = a; xb.f = b;
    return __builtin_amdgcn_perm(xb.u + 0x8000u, xa.u + 0x8000u, 0x07060302);
}

// async global->LDS, 16B/lane; LDS dest = wave-uniform base + lane*16
#define GLDS16(gp, lp) __builtin_amdgcn_global_load_lds( \
    (const __attribute__((address_space(1))) u32*)(const void*)(gp), \
    (__attribute__((address_space(3))) u32*)(void*)(lp), 16, 0, 0)

// ------------- merged Wq/Wk/Wv transpose + bf16 convert: dst[h][n][k] = bf16(src[h][k][n]) -----
// z = 0..47: matrix = z/16, head = z%16. R=1024 (k), C=64 (n).
__global__ __launch_bounds__(256)
void transpose_qkv_w(const float* __restrict__ s0, const float* __restrict__ s1,
                     const float* __restrict__ s2, u16* __restrict__ d0,
                     u16* __restrict__ d1, u16* __restrict__ d2) {
    int z = blockIdx.z;
    int which = z >> 4, h = z & 15;
    const float* src = (which == 0) ? s0 : (which == 1) ? s1 : s2;
    u16* dst = (which == 0) ? d0 : (which == 1) ? d1 : d2;
    src += (long)h * 1024 * 64;
    dst += (long)h * 64 * 1024;
    __shared__ float tile[32][33];
    int r0 = blockIdx.y * 32, c0 = blockIdx.x * 32;
    int tc = threadIdx.x & 31, tr = threadIdx.x >> 5;
    for (int j = 0; j < 4; j++) {
        int r = tr + j * 8;
        tile[r][tc] = src[(long)(r0 + r) * 64 + c0 + tc];
    }
    __syncthreads();
    for (int j = 0; j < 4; j++) {
        int rr = tr + j * 8;
        dst[(long)(c0 + rr) * 1024 + r0 + tc] = f2bf(tile[tc][rr]);
    }
}

// ---------------- Wo transpose: dst[n][k] = bf16(src[k][n]), 1024x1024 ----------------
__global__ __launch_bounds__(256)
void transpose_wo(const float* __restrict__ src, u16* __restrict__ dst) {
    __shared__ float tile[32][33];
    int r0 = blockIdx.y * 32, c0 = blockIdx.x * 32;
    int tc = threadIdx.x & 31, tr = threadIdx.x >> 5;
    for (int j = 0; j < 4; j++) {
        int r = tr + j * 8;
        tile[r][tc] = src[(long)(r0 + r) * 1024 + c0 + tc];
    }
    __syncthreads();
    for (int j = 0; j < 4; j++) {
        int rr = tr + j * 8;
        dst[(long)(c0 + rr) * 1024 + r0 + tc] = f2bf(tile[tc][rr]);
    }
}

// ---------------- fp32 -> bf16 bulk convert (vectorized) ----------------
__global__ __launch_bounds__(256)
void cvt_f32_bf16(const float* __restrict__ src, u16* __restrict__ dst, int n4) {
    int i = blockIdx.x * 256 + threadIdx.x;
    int stride = gridDim.x * 256;
    for (; i < n4; i += stride) {
        float4 v = ((const float4*)src)[i];
        uint2 o; o.x = pack2bf(v.x, v.y); o.y = pack2bf(v.z, v.w);
        ((uint2*)dst)[i] = o;
    }
}

// ---------------- GEMM: C[M=8192][N=1024] = (A[M][1024](bf16) * Bt^T + bias) * cscale ---------
// Ping-pong dbuf global_load_lds staging (1 barrier per BK=64 tile), XOR chunk swizzle.
// OUTMODE: 0 = fp32 [m][DM]; 1 = bf16 heads [b,h,s,d]; 2 = bf16 heads transposed [b,h,d,s]
template<int OUTMODE>
__global__ __launch_bounds__(256)
void gemm_bf16(const u16* __restrict__ A, const u16* __restrict__ Bt,
               const float* __restrict__ bias, void* __restrict__ Cptr, float cscale) {
    const int bm0 = blockIdx.x * 128;
    const int bn0 = blockIdx.y * 128;
    __shared__ __align__(16) u16 AsL[2][128 * 64];
    __shared__ __align__(16) u16 BsL[2][128 * 64];
    const int tid = threadIdx.x;
    const int lane = tid & 63;
    const int wave = tid >> 6;
    const int wm = (wave >> 1) * 64, wn = (wave & 1) * 64;
    const int l15 = lane & 15, quad = lane >> 4;

    f32x4 acc[4][4];
    for (int i = 0; i < 4; i++) for (int j = 0; j < 4; j++) acc[i][j] = (f32x4)0.0f;

    int rr[4], cc[4];
    for (int j = 0; j < 4; j++) {
        int ci = (wave * 4 + j) * 64 + lane;
        rr[j] = ci >> 3;
        cc[j] = (ci & 7) ^ (rr[j] & 7);
    }
    const int swz = l15 & 7;

    for (int j = 0; j < 4; j++)
        GLDS16(A + (size_t)(bm0 + rr[j]) * DM + cc[j] * 8, &AsL[0][(wave * 4 + j) * 512]);
    for (int j = 0; j < 4; j++)
        GLDS16(Bt + (size_t)(bn0 + rr[j]) * DM + cc[j] * 8, &BsL[0][(wave * 4 + j) * 512]);

    int buf = 0;
    for (int kk = 0; kk < DM; kk += 64) {
        __syncthreads();
        if (kk + 64 < DM) {
            for (int j = 0; j < 4; j++)
                GLDS16(A + (size_t)(bm0 + rr[j]) * DM + kk + 64 + cc[j] * 8, &AsL[buf ^ 1][(wave * 4 + j) * 512]);
            for (int j = 0; j < 4; j++)
                GLDS16(Bt + (size_t)(bn0 + rr[j]) * DM + kk + 64 + cc[j] * 8, &BsL[buf ^ 1][(wave * 4 + j) * 512]);
        }
        for (int ks = 0; ks < 2; ks++) {
            bf16x8 a[4], b[4];
            const int fo = ((ks * 4 + quad) ^ swz) * 8;
            for (int mi = 0; mi < 4; mi++)
                a[mi] = *(const bf16x8*)&AsL[buf][(wm + mi * 16 + l15) * 64 + fo];
            for (int ni = 0; ni < 4; ni++)
                b[ni] = *(const bf16x8*)&BsL[buf][(wn + ni * 16 + l15) * 64 + fo];
            for (int mi = 0; mi < 4; mi++)
                for (int ni = 0; ni < 4; ni++)
                    acc[mi][ni] = __builtin_amdgcn_mfma_f32_16x16x32_bf16(a[mi], b[ni], acc[mi][ni], 0, 0, 0);
        }
        buf ^= 1;
    }
    for (int mi = 0; mi < 4; mi++) {
        for (int ni = 0; ni < 4; ni++) {
            int n = bn0 + wn + ni * 16 + l15;
            float bb = bias[n];
            int m0 = bm0 + wm + mi * 16 + quad * 4;
            float v0 = (acc[mi][ni][0] + bb) * cscale, v1 = (acc[mi][ni][1] + bb) * cscale;
            float v2 = (acc[mi][ni][2] + bb) * cscale, v3 = (acc[mi][ni][3] + bb) * cscale;
            if (OUTMODE == 0) {
                float* C = (float*)Cptr;
                C[(size_t)(m0 + 0) * DM + n] = v0;
                C[(size_t)(m0 + 1) * DM + n] = v1;
                C[(size_t)(m0 + 2) * DM + n] = v2;
                C[(size_t)(m0 + 3) * DM + n] = v3;
            } else if (OUTMODE == 1) {
                u16* C = (u16*)Cptr;
                int b = m0 >> 11, s = m0 & 2047;
                int h = n >> 6, d = n & 63;
                size_t base = (((size_t)(b * NH + h)) * SEQ + s) * DKV + d;
                C[base + 0 * DKV] = f2bf1(v0);
                C[base + 1 * DKV] = f2bf1(v1);
                C[base + 2 * DKV] = f2bf1(v2);
                C[base + 3 * DKV] = f2bf1(v3);
            } else {
                u16* C = (u16*)Cptr;
                int b = m0 >> 11, s = m0 & 2047;
                int h = n >> 6, d = n & 63;
                uint2 pk; pk.x = pack2bf(v0, v1); pk.y = pack2bf(v2, v3);
                *(uint2*)&C[(((size_t)(b * NH + h)) * DKV + d) * SEQ + s] = pk;
            }
        }
    }
}

// ---------------- flash attention v8: v5 + ZER (exact) + native exp2 ----------------
// 64 q per wave, 256 q per block. qh pre-scaled by 0.125*log2(e); no-max softmax;
// S^T = K Q^T; l via ones-row MFMA; O^T = V^T P^T; ping-pong dbuf K/V.
// v8 = v5 with ONLY the provably-exact VALU cuts kept:
//   - ks=0 QK^T MFMA consumes loop-invariant ZERO C-operand (kills 64 v_mov/tile)
//   - exp2f -> __builtin_amdgcn_exp2f (OCML exp2f maps to this anyway; no numeric change)
//   - pack2bf (round-half-up) EVERYWHERE: v_cvt_pk_bf16_f32 failed correctness in r1/r2.
__global__ __launch_bounds__(256, 2)
void attn_kernel(const u16* __restrict__ qh, const u16* __restrict__ kh,
                 const u16* __restrict__ vt, u16* __restrict__ ctx) {
    const int qblk = blockIdx.x;   // 8
    const int h = blockIdx.y;      // 16
    const int b = blockIdx.z;      // 4
    const int tid = threadIdx.x;
    const int lane = tid & 63;
    const int wave = tid >> 6;
    const int l15 = lane & 15, quad = lane >> 4;
    const size_t headoff = ((size_t)(b * NH + h)) * SEQ * DKV;
    const u16* Q = qh + headoff;
    const u16* K = kh + headoff;       // [s][dk]
    const u16* V = vt + headoff;       // [dv][s]  (transposed)
    const int q0 = qblk * 256 + wave * 64;

    __shared__ __align__(16) u16 KsL[2][64 * 64];
    __shared__ __align__(16) u16 VtL[2][64 * 64];
    __shared__ __align__(16) u16 Ps[4][64][72];   // 144B rows: 16B-aligned, 2-way banks (free)

    // Q fragments: B-operand for S^T = K Q^T (col q = ni*16+l15, k = ks*32+quad*8)
    bf16x8 aq[4][2];
    for (int ni = 0; ni < 4; ni++)
        for (int ks = 0; ks < 2; ks++)
            aq[ni][ks] = *(const bf16x8*)&Q[(size_t)(q0 + ni * 16 + l15) * DKV + ks * 32 + quad * 8];

    bf16x8 vones;
    for (int j = 0; j < 8; j++) vones[j] = (short)0x3F80;   // bf16 1.0

    const f32x4 ZER = (f32x4)0.0f;     // loop-invariant C-operand for first QK^T MFMA

    f32x4 ot[4][4];   // row dv = di*16+quad*4+reg, col q = ni*16+l15
    for (int di = 0; di < 4; di++) for (int ni = 0; ni < 4; ni++) ot[di][ni] = (f32x4)0.0f;
    f32x4 lacc[4];
    for (int ni = 0; ni < 4; ni++) lacc[ni] = (f32x4)0.0f;

    int rr[2], cc[2];
    for (int j = 0; j < 2; j++) {
        int ci = (wave * 2 + j) * 64 + lane;
        rr[j] = ci >> 3;
        cc[j] = (ci & 7) ^ (rr[j] & 7);
    }
    const int swz = l15 & 7;

    for (int j = 0; j < 2; j++) {
        GLDS16(K + (size_t)rr[j] * DKV + cc[j] * 8, &KsL[0][(wave * 2 + j) * 512]);
        GLDS16(V + (size_t)rr[j] * SEQ + cc[j] * 8, &VtL[0][(wave * 2 + j) * 512]);
    }

    int buf = 0;
    for (int kv0 = 0; kv0 < SEQ; kv0 += 64) {
        __syncthreads();
        if (kv0 + 64 < SEQ) {
            int nx = kv0 + 64;
            for (int j = 0; j < 2; j++) {
                GLDS16(K + (size_t)(nx + rr[j]) * DKV + cc[j] * 8, &KsL[buf ^ 1][(wave * 2 + j) * 512]);
                GLDS16(V + (size_t)rr[j] * SEQ + nx + cc[j] * 8, &VtL[buf ^ 1][(wave * 2 + j) * 512]);
            }
        }

        // S^T: row kv = mi*16+quad*4+reg, col q = ni*16+l15 (pre-scaled to exp2 domain)
        // ks=0 consumes ZER (no per-tile accumulator zeroing), ks=1 accumulates.
        f32x4 st[4][4];
        {
            const int fo0 = (quad ^ swz) * 8;
            bf16x8 bk[4];
            for (int mi = 0; mi < 4; mi++)
                bk[mi] = *(const bf16x8*)&KsL[buf][(mi * 16 + l15) * 64 + fo0];
            for (int mi = 0; mi < 4; mi++)
                for (int ni = 0; ni < 4; ni++)
                    st[mi][ni] = __builtin_amdgcn_mfma_f32_16x16x32_bf16(bk[mi], aq[ni][0], ZER, 0, 0, 0);
            const int fo1 = ((4 + quad) ^ swz) * 8;
            for (int mi = 0; mi < 4; mi++)
                bk[mi] = *(const bf16x8*)&KsL[buf][(mi * 16 + l15) * 64 + fo1];
            for (int mi = 0; mi < 4; mi++)
                for (int ni = 0; ni < 4; ni++)
                    st[mi][ni] = __builtin_amdgcn_mfma_f32_16x16x32_bf16(bk[mi], aq[ni][1], st[mi][ni], 0, 0, 0);
        }

        // p = exp2(s) via v_exp_f32; pack with round-half-up pack2bf (proven)
        for (int ni = 0; ni < 4; ni++) {
            for (int mi = 0; mi < 4; mi++) {
                float e0 = __builtin_amdgcn_exp2f(st[mi][ni].x);
                float e1 = __builtin_amdgcn_exp2f(st[mi][ni].y);
                float e2 = __builtin_amdgcn_exp2f(st[mi][ni].z);
                float e3 = __builtin_amdgcn_exp2f(st[mi][ni].w);
                uint2 pk; pk.x = pack2bf(e0, e1); pk.y = pack2bf(e2, e3);
                *(uint2*)&Ps[wave][ni * 16 + l15][mi * 16 + quad * 4] = pk;
            }
        }
        __threadfence_block();   // wave-local Ps write->read ordering

        // O^T += V^T P^T ; l += ones * P^T
        for (int ks = 0; ks < 2; ks++) {
            const int fo = ((ks * 4 + quad) ^ swz) * 8;
            bf16x8 av[4], bp[4];
            for (int di = 0; di < 4; di++)
                av[di] = *(const bf16x8*)&VtL[buf][(di * 16 + l15) * 64 + fo];
            for (int ni = 0; ni < 4; ni++)
                bp[ni] = *(const bf16x8*)&Ps[wave][ni * 16 + l15][ks * 32 + quad * 8];
            for (int di = 0; di < 4; di++)
                for (int ni = 0; ni < 4; ni++)
                    ot[di][ni] = __builtin_amdgcn_mfma_f32_16x16x32_bf16(av[di], bp[ni], ot[di][ni], 0, 0, 0);
            for (int ni = 0; ni < 4; ni++)
                lacc[ni] = __builtin_amdgcn_mfma_f32_16x16x32_bf16(vones, bp[ni], lacc[ni], 0, 0, 0);
        }
        buf ^= 1;
    }

    // epilogue: ctx[b][q][h*64+dv], q = ni*16+l15, dv = di*16+quad*4+reg
    for (int ni = 0; ni < 4; ni++) {
        float inv = 1.0f / lacc[ni][0];   // 4 regs identical (ones rows)
        int srow = q0 + ni * 16 + l15;
        for (int di = 0; di < 4; di++) {
            uint2 pk;
            pk.x = pack2bf(ot[di][ni].x * inv, ot[di][ni].y * inv);
            pk.y = pack2bf(ot[di][ni].z * inv, ot[di][ni].w * inv);
            *(uint2*)&ctx[((size_t)b * SEQ + srow) * DM + h * DKV + di * 16 + quad * 4] = pk;
        }
    }
}

extern "C" void kernel_launch(void* const* d_in, const int* in_sizes, int n_in,
                              void* d_out, int out_size, void* d_ws, size_t ws_size,
                              hipStream_t stream) {
    const float* q  = (const float*)d_in[0];
    const float* k  = (const float*)d_in[1];
    const float* v  = (const float*)d_in[2];
    const float* Wq = (const float*)d_in[3];
    const float* bq = (const float*)d_in[4];
    const float* Wk = (const float*)d_in[5];
    const float* bk = (const float*)d_in[6];
    const float* Wv = (const float*)d_in[7];
    const float* bv = (const float*)d_in[8];
    const float* Wo = (const float*)d_in[9];
    const float* bo = (const float*)d_in[10];
    float* out = (float*)d_out;

    char* ws = (char*)d_ws;
    const size_t MB = 1024 * 1024;
    u16* WqT = (u16*)(ws + 0 * MB);
    u16* WkT = (u16*)(ws + 2 * MB);
    u16* WvT = (u16*)(ws + 4 * MB);
    u16* WoT = (u16*)(ws + 6 * MB);
    u16* qh  = (u16*)(ws + 8 * MB);
    u16* kh  = (u16*)(ws + 24 * MB);
    u16* vh  = (u16*)(ws + 40 * MB);   // transposed [b][h][dv][s]
    u16* ctx = (u16*)(ws + 56 * MB);
    u16* cvt = ctx;                    // reuse: converts dead before attn writes ctx
    // total ws use: 72 MB

    const int n4 = NB * SEQ * DM / 4;
    const float SC = 0.125f * 1.44269504088896f;  // (1/sqrt(dk)) * log2(e) baked into qh

    transpose_qkv_w<<<dim3(2, 32, 48), 256, 0, stream>>>(Wq, Wk, Wv, WqT, WkT, WvT);
    transpose_wo<<<dim3(32, 32), 256, 0, stream>>>(Wo, WoT);

    cvt_f32_bf16<<<dim3(2048), 256, 0, stream>>>(q, cvt, n4);
    gemm_bf16<1><<<dim3(64, 8), 256, 0, stream>>>(cvt, WqT, bq, qh, SC);
    cvt_f32_bf16<<<dim3(2048), 256, 0, stream>>>(k, cvt, n4);
    gemm_bf16<1><<<dim3(64, 8), 256, 0, stream>>>(cvt, WkT, bk, kh, 1.0f);
    cvt_f32_bf16<<<dim3(2048), 256, 0, stream>>>(v, cvt, n4);
    gemm_bf16<2><<<dim3(64, 8), 256, 0, stream>>>(cvt, WvT, bv, vh, 1.0f);

    attn_kernel<<<dim3(8, 16, 4), 256, 0, stream>>>(qh, kh, vh, ctx);

    gemm_bf16<0><<<dim3(64, 8), 256, 0, stream>>>(ctx, WoT, bo, out, 1.0f);
}